// Round 2
// baseline (496.996 us; speedup 1.0000x reference)
//
#include <hip/hip_runtime.h>

#define B_ROWS 16384
#define PDIM 196
#define KPAD 224
#define NV 24
#define OUT_DIM 1024
#define SLOPE 0.2f

typedef __attribute__((ext_vector_type(8))) short short8;     // 8 bf16 (4 VGPRs)
typedef __attribute__((ext_vector_type(4))) float floatx4;    // 4 fp32 acc

static __device__ __forceinline__ unsigned short f2bf(float f) {
    union { float f; unsigned int u; } v; v.f = f;
    unsigned int r = v.u + 0x7fffu + ((v.u >> 16) & 1u);
    return (unsigned short)(r >> 16);
}

// ---- kernel 1: tiny prep -------------------------------------------------
// blocks [0,112): pack Wx into MFMA-B order (bf16):
//   Bp[((ks*64+ntg)*64+lane)*8+j] = Wx[n=ntg*16+(lane&15)][k=ks*32+(lane>>4)*8+j]
// blocks [112,144): cvec[o] = sum_p v[p]*Wi[o,p] + NV*b_aggre[o]
// NOTE: no nontemporal hints anywhere (R3: nt cost +58us on x/out).
__global__ __launch_bounds__(256) void prep_k(
        const int* __restrict__ idx,
        const float* __restrict__ W_idx,
        const float* __restrict__ b_idx,
        const float* __restrict__ W_aggre,
        const float* __restrict__ b_aggre,
        unsigned short* __restrict__ Bp,
        float* __restrict__ cvec) {
    int t = threadIdx.x;
    if (blockIdx.x < 112) {
        // ---- pack B ----
        int tid = blockIdx.x * 256 + t;          // < 7*64*64 = 28672
        int ks = tid >> 12;
        int rem = tid & 4095;
        int nt = rem >> 6;
        int lane = rem & 63;
        int n = nt * 16 + (lane & 15);
        int kb = ks * 32 + (lane >> 4) * 8;
        unsigned short* dst = Bp + (size_t)tid * 8;
        #pragma unroll
        for (int j = 0; j < 8; ++j) {
            int k = kb + j;
            float v = (k < PDIM) ? W_aggre[(size_t)n * (2 * PDIM) + k] : 0.f;
            dst[j] = f2bf(v);
        }
    } else {
        // ---- cvec ----
        __shared__ float v_sh[PDIM];
        __shared__ int idx_sh[NV];
        if (t < NV) idx_sh[t] = idx[t];
        __syncthreads();
        if (t < PDIM) {
            float bp = b_idx[t];
            float a = 0.f;
            #pragma unroll
            for (int k = 0; k < NV; ++k) {
                float z = W_idx[t * NV + idx_sh[k]] + bp;
                a += (z > 0.f) ? z : SLOPE * z;
            }
            v_sh[t] = a;
        }
        __syncthreads();
        int bc = blockIdx.x - 112;                 // 0..31
        int o = bc * 32 + (t >> 3);                // 32 outputs per block
        int pl = t & 7;                            // 8 lanes per output
        const float* wr = W_aggre + (size_t)o * (2 * PDIM) + PDIM;
        float a = 0.f;
        for (int p = pl; p < PDIM; p += 8) a += v_sh[p] * wr[p];
        a += __shfl_down(a, 4, 8);
        a += __shfl_down(a, 2, 8);
        a += __shfl_down(a, 1, 8);
        if (pl == 0) cvec[o] = a + (float)NV * b_aggre[o];
    }
}

// ---- kernel 2: fused reduce + GEMM ---------------------------------------
// One block per 16-row tile (1024 blocks). Phase 1 stages
//   s[row,k] = sum_c cnt[c]*x[row,k,c]   (k<196, zero-pad to 224)
// into 7 KB LDS directly in MFMA-A fragment order; phase 2: 4 waves x 256
// cols of 16x16x32 bf16 MFMA against L2-resident pre-packed Bp, epilogue
// adds cvec and stores. Eliminates the Sm HBM round-trip and the full
// device sync of the 2-kernel version; out-writes overlap x-reads via
// block churn (~2-3 blocks/CU resident).
__global__ __launch_bounds__(256) void fused_k(
        const float* __restrict__ x,
        const int* __restrict__ idx,
        const unsigned short* __restrict__ Bp,
        const float* __restrict__ cvec,
        float* __restrict__ out) {
    __shared__ float scnt[NV];
    __shared__ unsigned short sA[7 * 64 * 8] __attribute__((aligned(16)));  // 7168 B
    int t = threadIdx.x;
    int bg = blockIdx.x;                           // row-group 0..1023

    if (t < NV) {
        int c = 0;
        #pragma unroll
        for (int k = 0; k < NV; ++k) c += (idx[k] == t);
        scnt[t] = (float)c;
    }
    __syncthreads();

    // ---- phase 1: weighted channel reduction into A-fragment-order LDS ----
    // 16 rows x 224 kpad = 3584 slots, 14 per thread; consecutive lanes ->
    // consecutive p -> same 96B-stride x pattern as the old reduce kernel.
    #pragma unroll 4
    for (int i = 0; i < 14; ++i) {
        int sl = t + 256 * i;
        unsigned row16 = (unsigned)sl / 224u;      // 0..15 (magic-mul)
        unsigned p = (unsigned)sl - row16 * 224u;
        float a = 0.f;
        if (p < PDIM) {
            const float4* x4 = (const float4*)(x + ((size_t)(bg * 16 + row16) * PDIM + p) * NV);
            #pragma unroll
            for (int q = 0; q < 6; ++q) {
                float4 v = x4[q];
                a += scnt[4 * q + 0] * v.x + scnt[4 * q + 1] * v.y +
                     scnt[4 * q + 2] * v.z + scnt[4 * q + 3] * v.w;
            }
        }
        unsigned ks = p >> 5, qd = (p >> 3) & 3, j = p & 7;
        sA[(ks * 64 + qd * 16 + row16) * 8 + j] = (p < PDIM) ? f2bf(a) : (unsigned short)0;
    }
    __syncthreads();

    // ---- phase 2: GEMM 16 x 1024 x 224 ----
    int lane = t & 63, wave = t >> 6;
    int quad = lane >> 4, l15 = lane & 15;

    short8 af[7];
    #pragma unroll
    for (int ks = 0; ks < 7; ++ks)
        af[ks] = *(const short8*)(sA + (ks * 64 + lane) * 8);

    floatx4 acc[16];
    #pragma unroll
    for (int nt = 0; nt < 16; ++nt) acc[nt] = (floatx4){0.f, 0.f, 0.f, 0.f};

    // Bp fragment for (ks, ntg=wave*16+nt): lane-contiguous 1KB per load.
    const unsigned short* bbase = Bp + ((size_t)(wave * 16) * 64 + lane) * 8;
    #pragma unroll
    for (int ks = 0; ks < 7; ++ks) {
        #pragma unroll
        for (int nt = 0; nt < 16; ++nt) {
            short8 bf = *(const short8*)(bbase + (size_t)(ks * 64 + nt) * 64 * 8);
            acc[nt] = __builtin_amdgcn_mfma_f32_16x16x32_bf16(af[ks], bf, acc[nt], 0, 0, 0);
        }
    }

    // ---- epilogue: add cvec, store 16 rows x 256 cols per wave ----
    int row0 = bg * 16 + quad * 4;
    float* orow = out + (size_t)row0 * OUT_DIM + wave * 256 + l15;
    #pragma unroll
    for (int nt = 0; nt < 16; ++nt) {
        float cv = cvec[wave * 256 + nt * 16 + l15];
        float* po = orow + nt * 16;
        po[0 * OUT_DIM] = acc[nt][0] + cv;
        po[1 * OUT_DIM] = acc[nt][1] + cv;
        po[2 * OUT_DIM] = acc[nt][2] + cv;
        po[3 * OUT_DIM] = acc[nt][3] + cv;
    }
}

extern "C" void kernel_launch(void* const* d_in, const int* in_sizes, int n_in,
                              void* d_out, int out_size, void* d_ws, size_t ws_size,
                              hipStream_t stream) {
    const float* x       = (const float*)d_in[0];
    const int*   idx     = (const int*)d_in[1];
    const float* W_idx   = (const float*)d_in[2];
    const float* b_idx   = (const float*)d_in[3];
    const float* W_aggre = (const float*)d_in[4];
    const float* b_aggre = (const float*)d_in[5];
    float* out = (float*)d_out;

    char* ws = (char*)d_ws;
    float*          cvec = (float*)ws;                         // 4 KB
    unsigned short* Bp   = (unsigned short*)(ws + 4096);       // 448 KB

    hipLaunchKernelGGL(prep_k, dim3(144), dim3(256), 0, stream,
                       idx, W_idx, b_idx, W_aggre, b_aggre, Bp, cvec);
    hipLaunchKernelGGL(fused_k, dim3(B_ROWS / 16), dim3(256), 0, stream,
                       x, idx, Bp, cvec, out);
}

// Round 3
// 464.177 us; speedup vs baseline: 1.0707x; 1.0707x over previous
//
#include <hip/hip_runtime.h>

#define B_ROWS 16384
#define PDIM 196
#define KPAD 224
#define NV 24
#define OUT_DIM 1024
#define SLOPE 0.2f

typedef __attribute__((ext_vector_type(8))) short short8;     // 8 bf16 (4 VGPRs)
typedef __attribute__((ext_vector_type(4))) float floatx4;    // 4 fp32 acc

static __device__ __forceinline__ unsigned short f2bf(float f) {
    union { float f; unsigned int u; } v; v.f = f;
    unsigned int r = v.u + 0x7fffu + ((v.u >> 16) & 1u);
    return (unsigned short)(r >> 16);
}

// ---- kernel 1: tiny prep -------------------------------------------------
// blocks [0,112): pack Wx into MFMA-B order (bf16):
//   Bp[((ks*64+ntg)*64+lane)*8+j] = Wx[n=ntg*16+(lane&15)][k=ks*32+(lane>>4)*8+j]
// blocks [112,144): cvec[o] = sum_p v[p]*Wi[o,p] + NV*b_aggre[o]
__global__ __launch_bounds__(256) void prep_k(
        const int* __restrict__ idx,
        const float* __restrict__ W_idx,
        const float* __restrict__ b_idx,
        const float* __restrict__ W_aggre,
        const float* __restrict__ b_aggre,
        unsigned short* __restrict__ Bp,
        float* __restrict__ cvec) {
    int t = threadIdx.x;
    if (blockIdx.x < 112) {
        int tid = blockIdx.x * 256 + t;          // < 7*64*64 = 28672
        int ks = tid >> 12;
        int rem = tid & 4095;
        int nt = rem >> 6;
        int lane = rem & 63;
        int n = nt * 16 + (lane & 15);
        int kb = ks * 32 + (lane >> 4) * 8;
        unsigned short* dst = Bp + (size_t)tid * 8;
        #pragma unroll
        for (int j = 0; j < 8; ++j) {
            int k = kb + j;
            float v = (k < PDIM) ? W_aggre[(size_t)n * (2 * PDIM) + k] : 0.f;
            dst[j] = f2bf(v);
        }
    } else {
        __shared__ float v_sh[PDIM];
        __shared__ int idx_sh[NV];
        if (t < NV) idx_sh[t] = idx[t];
        __syncthreads();
        if (t < PDIM) {
            float bp = b_idx[t];
            float a = 0.f;
            #pragma unroll
            for (int k = 0; k < NV; ++k) {
                float z = W_idx[t * NV + idx_sh[k]] + bp;
                a += (z > 0.f) ? z : SLOPE * z;
            }
            v_sh[t] = a;
        }
        __syncthreads();
        int bc = blockIdx.x - 112;                 // 0..31
        int o = bc * 32 + (t >> 3);
        int pl = t & 7;
        const float* wr = W_aggre + (size_t)o * (2 * PDIM) + PDIM;
        float a = 0.f;
        for (int p = pl; p < PDIM; p += 8) a += v_sh[p] * wr[p];
        a += __shfl_down(a, 4, 8);
        a += __shfl_down(a, 2, 8);
        a += __shfl_down(a, 1, 8);
        if (pl == 0) cvec[o] = a + (float)NV * b_aggre[o];
    }
}

// ---- stage: weighted channel reduction of one 16-row group into LDS ------
// Writes A in MFMA fragment order: sbuf[(ks*64 + quad*16 + row)*8 + j]
// = s[row, ks*32+quad*8+j]. Consecutive lanes -> consecutive p.
static __device__ __forceinline__ void stage_tile(
        const float* __restrict__ x, const float* scnt,
        unsigned short* sbuf, int rowbase, int t) {
    #pragma unroll 4
    for (int i = 0; i < 14; ++i) {
        int sl = t + 256 * i;                      // 16*224 = 3584 slots
        unsigned row16 = (unsigned)sl / 224u;      // magic-mul
        unsigned p = (unsigned)sl - row16 * 224u;
        float a = 0.f;
        if (p < PDIM) {
            const float4* x4 = (const float4*)(x + ((size_t)(rowbase + row16) * PDIM + p) * NV);
            #pragma unroll
            for (int q = 0; q < 6; ++q) {
                float4 v = x4[q];
                a += scnt[4 * q + 0] * v.x + scnt[4 * q + 1] * v.y +
                     scnt[4 * q + 2] * v.z + scnt[4 * q + 3] * v.w;
            }
        }
        unsigned ks = p >> 5, qd = (p >> 3) & 3, j = p & 7;
        sbuf[(ks * 64 + qd * 16 + row16) * 8 + j] = (p < PDIM) ? f2bf(a) : (unsigned short)0;
    }
}

// ---- gemm: 16 x 1024 x 224 MFMA from staged A, store with cvec ------------
static __device__ __forceinline__ void gemm_tile(
        const unsigned short* sbuf, const unsigned short* __restrict__ Bp,
        const float* __restrict__ cvec, float* __restrict__ out,
        int rowbase, int t) {
    int lane = t & 63, wave = t >> 6;
    int quad = lane >> 4, l15 = lane & 15;

    short8 af[7];
    #pragma unroll
    for (int ks = 0; ks < 7; ++ks)
        af[ks] = *(const short8*)(sbuf + (ks * 64 + lane) * 8);

    floatx4 acc[16];
    #pragma unroll
    for (int nt = 0; nt < 16; ++nt) acc[nt] = (floatx4){0.f, 0.f, 0.f, 0.f};

    const unsigned short* bbase = Bp + ((size_t)(wave * 16) * 64 + lane) * 8;
    #pragma unroll
    for (int ks = 0; ks < 7; ++ks) {
        #pragma unroll
        for (int nt = 0; nt < 16; ++nt) {
            short8 bf = *(const short8*)(bbase + (size_t)(ks * 64 + nt) * 64 * 8);
            acc[nt] = __builtin_amdgcn_mfma_f32_16x16x32_bf16(af[ks], bf, acc[nt], 0, 0, 0);
        }
    }

    int row0 = rowbase + quad * 4;
    float* orow = out + (size_t)row0 * OUT_DIM + wave * 256 + l15;
    #pragma unroll
    for (int nt = 0; nt < 16; ++nt) {
        float cv = cvec[wave * 256 + nt * 16 + l15];
        float* po = orow + nt * 16;
        po[0 * OUT_DIM] = acc[nt][0] + cv;
        po[1 * OUT_DIM] = acc[nt][1] + cv;
        po[2 * OUT_DIM] = acc[nt][2] + cv;
        po[3 * OUT_DIM] = acc[nt][3] + cv;
    }
}

// ---- kernel 2: software-pipelined fused reduce+GEMM -----------------------
// Each block owns TWO 16-row groups with double-buffered LDS A-tiles:
//   stage(g0); bar; [stage(g1) || gemm(g0)]; bar; gemm(g1)
// stage's 84 independent x-loads are issued first (source order); their
// reduce+ds_write tails drain under gemm's ds_read/B-load/MFMA stream.
// R1 lesson: grid==resident means zero churn -> phases must overlap
// INSIDE the block, not via churn. Grid 512, 2 blocks/CU, LDS 14.4 KB.
__global__ __launch_bounds__(256) void fused_k(
        const float* __restrict__ x,
        const int* __restrict__ idx,
        const unsigned short* __restrict__ Bp,
        const float* __restrict__ cvec,
        float* __restrict__ out) {
    __shared__ float scnt[NV];
    __shared__ unsigned short sA[2][7 * 64 * 8] __attribute__((aligned(16)));
    int t = threadIdx.x;

    if (t < NV) {
        int c = 0;
        #pragma unroll
        for (int k = 0; k < NV; ++k) c += (idx[k] == t);
        scnt[t] = (float)c;
    }
    __syncthreads();

    int rb0 = blockIdx.x * 32;                     // two consecutive 16-row groups

    stage_tile(x, scnt, sA[0], rb0, t);
    __syncthreads();

    stage_tile(x, scnt, sA[1], rb0 + 16, t);       // overlaps with gemm below
    gemm_tile(sA[0], Bp, cvec, out, rb0, t);
    __syncthreads();

    gemm_tile(sA[1], Bp, cvec, out, rb0 + 16, t);
}

extern "C" void kernel_launch(void* const* d_in, const int* in_sizes, int n_in,
                              void* d_out, int out_size, void* d_ws, size_t ws_size,
                              hipStream_t stream) {
    const float* x       = (const float*)d_in[0];
    const int*   idx     = (const int*)d_in[1];
    const float* W_idx   = (const float*)d_in[2];
    const float* b_idx   = (const float*)d_in[3];
    const float* W_aggre = (const float*)d_in[4];
    const float* b_aggre = (const float*)d_in[5];
    float* out = (float*)d_out;

    char* ws = (char*)d_ws;
    float*          cvec = (float*)ws;                         // 4 KB
    unsigned short* Bp   = (unsigned short*)(ws + 4096);       // 448 KB

    hipLaunchKernelGGL(prep_k, dim3(144), dim3(256), 0, stream,
                       idx, W_idx, b_idx, W_aggre, b_aggre, Bp, cvec);
    hipLaunchKernelGGL(fused_k, dim3(B_ROWS / 32), dim3(256), 0, stream,
                       x, idx, Bp, cvec, out);
}

// Round 4
// 459.842 us; speedup vs baseline: 1.0808x; 1.0094x over previous
//
#include <hip/hip_runtime.h>

#define B_ROWS 16384
#define PDIM 196
#define KPAD 224
#define NV 24
#define OUT_DIM 1024
#define SLOPE 0.2f

typedef __attribute__((ext_vector_type(8))) short short8;     // 8 bf16 (4 VGPRs)
typedef __attribute__((ext_vector_type(4))) float floatx4;    // 4 fp32 acc

static __device__ __forceinline__ unsigned short f2bf(float f) {
    union { float f; unsigned int u; } v; v.f = f;
    unsigned int r = v.u + 0x7fffu + ((v.u >> 16) & 1u);
    return (unsigned short)(r >> 16);
}

// ---- kernel 1: tiny prep -------------------------------------------------
// blocks [0,112): pack Wx into MFMA-B order (bf16):
//   Bp[((ks*64+ntg)*64+lane)*8+j] = Wx[n=ntg*16+(lane&15)][k=ks*32+(lane>>4)*8+j]
// blocks [112,144): cvec[o] = sum_p v[p]*Wi[o,p] + NV*b_aggre[o]
__global__ __launch_bounds__(256) void prep_k(
        const int* __restrict__ idx,
        const float* __restrict__ W_idx,
        const float* __restrict__ b_idx,
        const float* __restrict__ W_aggre,
        const float* __restrict__ b_aggre,
        unsigned short* __restrict__ Bp,
        float* __restrict__ cvec) {
    int t = threadIdx.x;
    if (blockIdx.x < 112) {
        int tid = blockIdx.x * 256 + t;          // < 7*64*64 = 28672
        int ks = tid >> 12;
        int rem = tid & 4095;
        int nt = rem >> 6;
        int lane = rem & 63;
        int n = nt * 16 + (lane & 15);
        int kb = ks * 32 + (lane >> 4) * 8;
        unsigned short* dst = Bp + (size_t)tid * 8;
        #pragma unroll
        for (int j = 0; j < 8; ++j) {
            int k = kb + j;
            float v = (k < PDIM) ? W_aggre[(size_t)n * (2 * PDIM) + k] : 0.f;
            dst[j] = f2bf(v);
        }
    } else {
        __shared__ float v_sh[PDIM];
        __shared__ int idx_sh[NV];
        if (t < NV) idx_sh[t] = idx[t];
        __syncthreads();
        if (t < PDIM) {
            float bp = b_idx[t];
            float a = 0.f;
            #pragma unroll
            for (int k = 0; k < NV; ++k) {
                float z = W_idx[t * NV + idx_sh[k]] + bp;
                a += (z > 0.f) ? z : SLOPE * z;
            }
            v_sh[t] = a;
        }
        __syncthreads();
        int bc = blockIdx.x - 112;                 // 0..31
        int o = bc * 32 + (t >> 3);
        int pl = t & 7;
        const float* wr = W_aggre + (size_t)o * (2 * PDIM) + PDIM;
        float a = 0.f;
        for (int p = pl; p < PDIM; p += 8) a += v_sh[p] * wr[p];
        a += __shfl_down(a, 4, 8);
        a += __shfl_down(a, 2, 8);
        a += __shfl_down(a, 1, 8);
        if (pl == 0) cvec[o] = a + (float)NV * b_aggre[o];
    }
}

// ---- stage: full weighted channel reduction of one 16-row group ----------
static __device__ __forceinline__ void stage_tile(
        const float* __restrict__ x, const float* scnt,
        unsigned short* sbuf, int rowbase, int t) {
    #pragma unroll 4
    for (int i = 0; i < 14; ++i) {
        int sl = t + 256 * i;                      // 16*224 = 3584 slots
        unsigned row16 = (unsigned)sl / 224u;      // magic-mul
        unsigned p = (unsigned)sl - row16 * 224u;
        float a = 0.f;
        if (p < PDIM) {
            const float4* x4 = (const float4*)(x + ((size_t)(rowbase + row16) * PDIM + p) * NV);
            #pragma unroll
            for (int q = 0; q < 6; ++q) {
                float4 v = x4[q];
                a += scnt[4 * q + 0] * v.x + scnt[4 * q + 1] * v.y +
                     scnt[4 * q + 2] * v.z + scnt[4 * q + 3] * v.w;
            }
        }
        unsigned ks = p >> 5, qd = (p >> 3) & 3, j = p & 7;
        sbuf[(ks * 64 + qd * 16 + row16) * 8 + j] = (p < PDIM) ? f2bf(a) : (unsigned short)0;
    }
}

// ---- gemm: plain 16 x 1024 x 224 MFMA from staged A (no overlap) ----------
static __device__ __forceinline__ void gemm_tile(
        const unsigned short* sbuf, const unsigned short* __restrict__ Bp,
        const float* __restrict__ cvec, float* __restrict__ out,
        int rowbase, int t) {
    int lane = t & 63, wave = t >> 6;
    int quad = lane >> 4, l15 = lane & 15;

    short8 af[7];
    #pragma unroll
    for (int ks = 0; ks < 7; ++ks)
        af[ks] = *(const short8*)(sbuf + (ks * 64 + lane) * 8);

    floatx4 acc[16];
    #pragma unroll
    for (int nt = 0; nt < 16; ++nt) acc[nt] = (floatx4){0.f, 0.f, 0.f, 0.f};

    const unsigned short* bbase = Bp + ((size_t)(wave * 16) * 64 + lane) * 8;
    #pragma unroll
    for (int ks = 0; ks < 7; ++ks) {
        #pragma unroll
        for (int nt = 0; nt < 16; ++nt) {
            short8 bf = *(const short8*)(bbase + (size_t)(ks * 64 + nt) * 512);
            acc[nt] = __builtin_amdgcn_mfma_f32_16x16x32_bf16(af[ks], bf, acc[nt], 0, 0, 0);
        }
    }

    int row0 = rowbase + quad * 4;
    float* orow = out + (size_t)row0 * OUT_DIM + wave * 256 + l15;
    #pragma unroll
    for (int nt = 0; nt < 16; ++nt) {
        float cv = cvec[wave * 256 + nt * 16 + l15];
        float* po = orow + nt * 16;
        po[0 * OUT_DIM] = acc[nt][0] + cv;
        po[1 * OUT_DIM] = acc[nt][1] + cv;
        po[2 * OUT_DIM] = acc[nt][2] + cv;
        po[3 * OUT_DIM] = acc[nt][3] + cv;
    }
}

// ---- kernel 2: fused reduce+GEMM, instruction-level pipelined -------------
// Each block: two 16-row groups, double-buffered LDS A-tiles.
//   stage(g0); bar; [phase2: per-ks interleave of gemm(g0) + stage(g1)]; bar;
//   gemm(g1)
// Phase 2 per ks-step (fully unrolled, source order forces the schedule):
//   16 B-frag loads (L2) -> 12 x-loads for g1 (HBM, issue only) ->
//   16 MFMAs (vmcnt waits on B only; x-loads stay in flight) ->
//   consume x regs (FMA reduce + ds_write to sA[1]).
// R2 lesson: adjacent stage()/gemm() calls do NOT overlap — each wave runs
// them serially. The interleave must be at instruction granularity (T14
// issue-early/consume-late per chunk) so HBM reads issue continuously.
__global__ __launch_bounds__(256) void fused_k(
        const float* __restrict__ x,
        const int* __restrict__ idx,
        const unsigned short* __restrict__ Bp,
        const float* __restrict__ cvec,
        float* __restrict__ out) {
    __shared__ float scnt[NV];
    __shared__ unsigned short sA[2][7 * 64 * 8] __attribute__((aligned(16)));
    int t = threadIdx.x;

    if (t < NV) {
        int c = 0;
        #pragma unroll
        for (int k = 0; k < NV; ++k) c += (idx[k] == t);
        scnt[t] = (float)c;
    }
    __syncthreads();

    int rb0 = blockIdx.x * 32;                     // two consecutive 16-row groups

    stage_tile(x, scnt, sA[0], rb0, t);
    __syncthreads();

    // ---- phase 2: gemm(g0) interleaved with stage(g1) ----
    {
        int lane = t & 63, wave = t >> 6;
        int quad = lane >> 4, l15 = lane & 15;

        short8 af[7];
        #pragma unroll
        for (int ks = 0; ks < 7; ++ks)
            af[ks] = *(const short8*)(sA[0] + (ks * 64 + lane) * 8);

        floatx4 acc[16];
        #pragma unroll
        for (int nt = 0; nt < 16; ++nt) acc[nt] = (floatx4){0.f, 0.f, 0.f, 0.f};

        const unsigned short* bbase = Bp + ((size_t)(wave * 16) * 64 + lane) * 8;

        #pragma unroll
        for (int ks = 0; ks < 7; ++ks) {
            // B fragments for this ks (L2-resident, issued first)
            short8 bf[16];
            #pragma unroll
            for (int nt = 0; nt < 16; ++nt)
                bf[nt] = *(const short8*)(bbase + (size_t)(ks * 64 + nt) * 512);
            // issue 2 stage slots of g1 (HBM); consumed after the MFMAs
            float4 r[2][6];
            unsigned pp[2], rw[2];
            #pragma unroll
            for (int u = 0; u < 2; ++u) {
                int sl = t + 256 * (2 * ks + u);
                unsigned row16 = (unsigned)sl / 224u;
                unsigned p = (unsigned)sl - row16 * 224u;
                rw[u] = row16; pp[u] = p;
                if (p < PDIM) {
                    const float4* x4 = (const float4*)(x + ((size_t)(rb0 + 16 + row16) * PDIM + p) * NV);
                    #pragma unroll
                    for (int q = 0; q < 6; ++q) r[u][q] = x4[q];
                }
            }
            // MFMA cluster — depends only on bf (issued before the x-loads,
            // so its vmcnt wait leaves the x-loads in flight)
            #pragma unroll
            for (int nt = 0; nt < 16; ++nt)
                acc[nt] = __builtin_amdgcn_mfma_f32_16x16x32_bf16(af[ks], bf[nt], acc[nt], 0, 0, 0);
            // consume stage regs -> sA[1]
            #pragma unroll
            for (int u = 0; u < 2; ++u) {
                float a = 0.f;
                if (pp[u] < PDIM) {
                    #pragma unroll
                    for (int q = 0; q < 6; ++q) {
                        float4 v = r[u][q];
                        a += scnt[4 * q + 0] * v.x + scnt[4 * q + 1] * v.y +
                             scnt[4 * q + 2] * v.z + scnt[4 * q + 3] * v.w;
                    }
                }
                unsigned k2 = pp[u] >> 5, qd = (pp[u] >> 3) & 3, j = pp[u] & 7;
                sA[1][(k2 * 64 + qd * 16 + rw[u]) * 8 + j] =
                    (pp[u] < PDIM) ? f2bf(a) : (unsigned short)0;
            }
        }

        // epilogue for g0
        int row0 = rb0 + quad * 4;
        float* orow = out + (size_t)row0 * OUT_DIM + wave * 256 + l15;
        #pragma unroll
        for (int nt = 0; nt < 16; ++nt) {
            float cv = cvec[wave * 256 + nt * 16 + l15];
            float* po = orow + nt * 16;
            po[0 * OUT_DIM] = acc[nt][0] + cv;
            po[1 * OUT_DIM] = acc[nt][1] + cv;
            po[2 * OUT_DIM] = acc[nt][2] + cv;
            po[3 * OUT_DIM] = acc[nt][3] + cv;
        }
    }
    __syncthreads();

    gemm_tile(sA[1], Bp, cvec, out, rb0 + 16, t);
}

extern "C" void kernel_launch(void* const* d_in, const int* in_sizes, int n_in,
                              void* d_out, int out_size, void* d_ws, size_t ws_size,
                              hipStream_t stream) {
    const float* x       = (const float*)d_in[0];
    const int*   idx     = (const int*)d_in[1];
    const float* W_idx   = (const float*)d_in[2];
    const float* b_idx   = (const float*)d_in[3];
    const float* W_aggre = (const float*)d_in[4];
    const float* b_aggre = (const float*)d_in[5];
    float* out = (float*)d_out;

    char* ws = (char*)d_ws;
    float*          cvec = (float*)ws;                         // 4 KB
    unsigned short* Bp   = (unsigned short*)(ws + 4096);       // 448 KB

    hipLaunchKernelGGL(prep_k, dim3(144), dim3(256), 0, stream,
                       idx, W_idx, b_idx, W_aggre, b_aggre, Bp, cvec);
    hipLaunchKernelGGL(fused_k, dim3(B_ROWS / 32), dim3(256), 0, stream,
                       x, idx, Bp, cvec, out);
}